// Round 3
// baseline (195.749 us; speedup 1.0000x reference)
//
#include <hip/hip_runtime.h>
#include <stdint.h>

// Problem constants (from reference)
#define NB   4      // batch
#define CC   256    // channels (K)
#define WR   60     // cells per row/col
#define MM   3600   // HR*WR (M and N of the GEMM)
#define HH   480
#define WW   480
#define GS   8
#define MT   29     // ceil(3600/128) tiles per side
#define NBLK (MT * MT * NB)      // gemm grid size = 3364
#define PREPB 57                 // ceil(NB*MM / 256) blocks carrying prep work

typedef __bf16 bf16x8 __attribute__((ext_vector_type(8)));
typedef float  f32x4  __attribute__((ext_vector_type(4)));

// round-to-nearest-even fp32 -> bf16 (data has no NaN/inf)
__device__ __forceinline__ unsigned short f2bf(float x) {
  union { float f; unsigned u; } v; v.f = x;
  unsigned r = v.u + 0x7fffu + ((v.u >> 16) & 1u);
  return (unsigned short)(r >> 16);
}

// async global->LDS, 16B per lane; LDS dest is wave-uniform base + lane*16
__device__ __forceinline__ void gload_lds16(const void* g, void* l) {
  __builtin_amdgcn_global_load_lds(
      (const __attribute__((address_space(1))) void*)g,
      (__attribute__((address_space(3))) void*)l, 16, 0, 0);
}

// ---------------------------------------------------------------------------
// Kernel 1: pack desc[b][c][m] (f32) into MFMA-fragment-ordered bf16 tiles:
//   packed[b][mtile][kt][ ((h*4 + t)*64 + lane)*8 + e ]
// (m = mtile*128 + h*64 + t*16 + (lane&15), k = kt*32 + (lane>>4)*8 + e).
// Tail rows (m >= 3600) zero-filled -> GEMM needs no m-guard.
// FUSED: blocks 0..56 also do the per-cell prep (homography warp, vis-mask
// 8x8 product, per-block vm partial sums); block 0 zeroes loss+counter.
// ---------------------------------------------------------------------------
__global__ __launch_bounds__(256) void pack_prep(
    const float* __restrict__ d1, const float* __restrict__ d2,
    const float* __restrict__ homo, const float* __restrict__ vis,
    unsigned short* __restrict__ p1, unsigned short* __restrict__ p2,
    float2* __restrict__ wg, float* __restrict__ vmarr,
    float* __restrict__ vm_part, float* __restrict__ loss_sum,
    unsigned* __restrict__ counter) {
  __shared__ float tile[32][132];   // [k_local][m_local]; rows 528B (16B-aligned)
  int kt = blockIdx.x, mtile = blockIdx.y, z = blockIdx.z;
  int bid = kt + 8 * (mtile + MT * z);
  int b = z & 3;
  const float* src = ((z >> 2) ? d2 : d1) + (size_t)b * CC * MM + (size_t)(kt * 32) * MM;
  unsigned short* dst = ((z >> 2) ? p2 : p1) + ((size_t)(b * MT + mtile) * 8 + kt) * 4096;
  int tid = threadIdx.x;

  if (bid == 0 && tid == 0) { loss_sum[0] = 0.f; *counter = 0u; }

  // coalesced read: 32 k-rows x 128 m (float4 along m)
#pragma unroll
  for (int pass = 0; pass < 4; ++pass) {
    int cid = pass * 256 + tid;          // [0,1024)
    int c = cid >> 5, m4 = (cid & 31) * 4;
    int gm = mtile * 128 + m4;
    float4 v;
    if (gm + 3 < MM) {
      v = *(const float4*)(src + (size_t)c * MM + gm);
    } else {
      v.x = (gm     < MM) ? src[(size_t)c * MM + gm]     : 0.f;
      v.y = (gm + 1 < MM) ? src[(size_t)c * MM + gm + 1] : 0.f;
      v.z = (gm + 2 < MM) ? src[(size_t)c * MM + gm + 2] : 0.f;
      v.w = (gm + 3 < MM) ? src[(size_t)c * MM + gm + 3] : 0.f;
    }
    *(float4*)&tile[c][m4] = v;
  }
  __syncthreads();

  // fragment-order write: 512 slots of 16B; slot s = ((h*4+t)*64 + lane)
#pragma unroll
  for (int pass = 0; pass < 2; ++pass) {
    int s = pass * 256 + tid;            // [0,512)
    int lane = s & 63, tt = (s >> 6) & 3, h = s >> 8;
    int m_local = h * 64 + tt * 16 + (lane & 15);
    int k_local = (lane >> 4) * 8;
    unsigned short o[8];
    if (mtile * 128 + m_local < MM) {
#pragma unroll
      for (int e = 0; e < 8; ++e) o[e] = f2bf(tile[k_local + e][m_local]);
    } else {
#pragma unroll
      for (int e = 0; e < 8; ++e) o[e] = 0;
    }
    ((uint4*)dst)[s] = *(const uint4*)o;
  }

  // ---- fused prep (blocks 0..56 only; block-uniform branch) ----
  if (bid < PREPB) {
    int idx = bid * 256 + tid;
    float p = 0.f;
    if (idx < NB * MM) {
      int bb = idx / MM, cell = idx - bb * MM;
      int h1 = cell / WR, w1 = cell - h1 * WR;
      float gx = (float)(w1 * GS + GS / 2);
      float gy = (float)(h1 * GS + GS / 2);
      const float* Hm = homo + bb * 9;
      float X = Hm[0] * gx + Hm[1] * gy + Hm[2];
      float Y = Hm[3] * gx + Hm[4] * gy + Hm[5];
      float Z = Hm[6] * gx + Hm[7] * gy + Hm[8];
      wg[idx] = make_float2(X / Z, Y / Z);
      const float* v = vis + (size_t)bb * HH * WW + (size_t)(h1 * GS) * WW + w1 * GS;
      float prod = 1.f;
#pragma unroll
      for (int rr = 0; rr < GS; ++rr) {
        const float4* rp = (const float4*)(v + (size_t)rr * WW);
        float4 a = rp[0], c = rp[1];
        prod *= a.x * a.y * a.z * a.w;
        prod *= c.x * c.y * c.z * c.w;
      }
      vmarr[idx] = prod;
      p = prod;
    }
#pragma unroll
    for (int off = 32; off; off >>= 1) p += __shfl_down(p, off, 64);
    __syncthreads();                      // tile LDS reuse safety
    if ((tid & 63) == 0) ((float*)tile)[tid >> 6] = p;
    __syncthreads();
    if (tid == 0)
      vm_part[bid] = ((float*)tile)[0] + ((float*)tile)[1] +
                     ((float*)tile)[2] + ((float*)tile)[3];
  }
}

// ---------------------------------------------------------------------------
// Kernel 2: fused bf16 MFMA GEMM + hinge loss + global reduce + finalize.
// A panel (128 rows x K=256 = 64 KB) LDS-resident, staged once with 16
// deep-pipelined global_load_lds per thread. B double-buffered 2x8KB: the
// prefetch of B(kt+1) is issued before compute(kt), so the vmcnt(0) drain at
// the end-of-iter barrier lands AFTER compute -> load latency hidden.
// LDS total = 81920 B exactly -> 2 blocks/CU. Last block finalizes output.
// ---------------------------------------------------------------------------
__global__ __launch_bounds__(256, 2) void hinge_gemm(
    const unsigned short* __restrict__ Ap, const unsigned short* __restrict__ Bp,
    const float2* __restrict__ wg, const float* __restrict__ vmarr,
    const float* __restrict__ vm_part, float* __restrict__ loss_sum,
    unsigned* __restrict__ counter, float* __restrict__ out) {
  __shared__ unsigned short As[32768];   // 64 KB: full A panel (8 kt-tiles)
  __shared__ unsigned short Bs[8192];    // 16 KB: 2 x 8 KB B dbuf

  int b = blockIdx.z, mtile = blockIdx.y, ntile = blockIdx.x;
  int tid = threadIdx.x, lane = tid & 63, w = tid >> 6;
  int quad = lane >> 4, r = lane & 15;
  int wave_m = w >> 1, wave_n = w & 1;

  const char* Ag = (const char*)(Ap + ((size_t)(b * MT + mtile) * 8) * 4096);
  const char* Bg = (const char*)(Bp + ((size_t)(b * MT + ntile) * 8) * 4096);
  char* AsB = (char*)As;
  char* BsB = (char*)Bs;

  // stage full A panel + B(kt=0); all 18 loads in flight, one drain at barrier
#pragma unroll
  for (int j = 0; j < 16; ++j)
    gload_lds16(Ag + j * 4096 + tid * 16, AsB + j * 4096 + w * 1024);
  gload_lds16(Bg + tid * 16,        BsB + w * 1024);
  gload_lds16(Bg + 4096 + tid * 16, BsB + 4096 + w * 1024);

  f32x4 acc[4][4];
#pragma unroll
  for (int i = 0; i < 4; ++i)
#pragma unroll
    for (int j = 0; j < 4; ++j)
#pragma unroll
      for (int k = 0; k < 4; ++k) acc[i][j][k] = 0.f;

  __syncthreads();

#pragma unroll
  for (int kt = 0; kt < 8; ++kt) {
    if (kt < 7) {   // prefetch B(kt+1) into the other buffer
      const char* gb = Bg + (kt + 1) * 8192;
      char* bn = BsB + ((kt + 1) & 1) * 8192;
      gload_lds16(gb + tid * 16,        bn + w * 1024);
      gload_lds16(gb + 4096 + tid * 16, bn + 4096 + w * 1024);
    }
    const char* pa = AsB + kt * 8192 + wave_m * 4096 + lane * 16;
    const char* pb = BsB + (kt & 1) * 8192 + wave_n * 4096 + lane * 16;
    bf16x8 af[4], bfr[4];
#pragma unroll
    for (int t = 0; t < 4; ++t) {
      af[t]  = *(const bf16x8*)(pa + t * 1024);
      bfr[t] = *(const bf16x8*)(pb + t * 1024);
    }
#pragma unroll
    for (int mt = 0; mt < 4; ++mt)
#pragma unroll
      for (int nt = 0; nt < 4; ++nt)
        acc[mt][nt] = __builtin_amdgcn_mfma_f32_16x16x32_bf16(
            af[mt], bfr[nt], acc[mt][nt], 0, 0, 0);
    __syncthreads();   // drains B(kt+1) (overlapped with compute) + buf reuse
  }

  // Epilogue. C/D layout: col(n) = lane&15, row(m) = quad*4 + reg.
  // Tail m-rows are zero-padded in Ap -> dot=0 -> hinge=0; no m-guard needed.
  float gxv[16], gyv[16];
#pragma unroll
  for (int mt = 0; mt < 4; ++mt)
#pragma unroll
    for (int reg = 0; reg < 4; ++reg) {
      int gm = mtile * 128 + wave_m * 64 + mt * 16 + quad * 4 + reg;
      float gmf = (float)gm;
      float h1 = floorf(fmaf(gmf, (1.0f / 60.0f), (1.0f / 120.0f)));
      float w1 = fmaf(h1, -60.f, gmf);
      gxv[mt * 4 + reg] = fmaf(w1, 8.f, 4.f);
      gyv[mt * 4 + reg] = fmaf(h1, 8.f, 4.f);
    }

  float sum = 0.f;
  const float2* wgb = wg + (size_t)b * MM;
  const float*  vmb = vmarr + (size_t)b * MM;
#pragma unroll
  for (int nt = 0; nt < 4; ++nt) {
    int gn = ntile * 128 + wave_n * 64 + nt * 16 + r;
    bool nok = gn < MM;
    float2 wgv = nok ? wgb[gn] : make_float2(1e9f, 1e9f);
    float  vmv = nok ? vmb[gn] : 0.f;
#pragma unroll
    for (int mt = 0; mt < 4; ++mt)
#pragma unroll
      for (int reg = 0; reg < 4; ++reg) {
        float dot = acc[mt][nt][reg];
        float dx = gxv[mt * 4 + reg] - wgv.x;
        float dy = gyv[mt * 4 + reg] - wgv.y;
        float d2 = fmaf(dx, dx, dy * dy);
        float a = (d2 <= 56.25f) ? (1.0f - dot) : (dot - 0.2f);
        sum = fmaf(vmv, fmaxf(a, 0.f), sum);
      }
  }
#pragma unroll
  for (int off = 32; off; off >>= 1) sum += __shfl_down(sum, off, 64);
  if (lane == 0) ((float*)As)[w] = sum;   // reuse As (all LDS reads done)
  __syncthreads();
  if (tid == 0) {
    float bs = ((float*)As)[0] + ((float*)As)[1] +
               ((float*)As)[2] + ((float*)As)[3];
    atomicAdd(loss_sum, bs);
    __threadfence();
    unsigned old = atomicAdd(counter, 1u);
    if (old == (unsigned)NBLK - 1u) {     // last block: finalize
      float vs = 0.f;
      for (int i = 0; i < PREPB; ++i) vs += vm_part[i];
      float lt = atomicAdd(loss_sum, 0.f);  // atomic read: all adds visible
      out[0] = lt / ((float)MM * vs);
    }
  }
}

extern "C" void kernel_launch(void* const* d_in, const int* in_sizes, int n_in,
                              void* d_out, int out_size, void* d_ws, size_t ws_size,
                              hipStream_t stream) {
  const float* desc1 = (const float*)d_in[0];
  const float* desc2 = (const float*)d_in[1];
  const float* homo  = (const float*)d_in[2];
  const float* vis   = (const float*)d_in[3];
  float* out = (float*)d_out;

  char* ws = (char*)d_ws;
  // packed size per desc: 4 * 29 * 8 * 4096 elems * 2B = 7,602,176 B
  unsigned short* Ap = (unsigned short*)ws;
  unsigned short* Bp = (unsigned short*)(ws + 7602176);
  float2*   wg      = (float2*)(ws + 15204352);          // 115,200 B
  float*    vm      = (float*) (ws + 15319552);          //  57,600 B
  float*    vm_part = (float*) (ws + 15377152);          // 57 * 4 B
  float*    sums    = (float*) (ws + 15377408);          // loss accumulator
  unsigned* counter = (unsigned*)(ws + 15377412);

  dim3 pgrid(8, MT, 2 * NB);   // kt x mtile x (desc,b); fused prep + zero-init
  pack_prep<<<pgrid, 256, 0, stream>>>(desc1, desc2, homo, vis, Ap, Bp,
                                       wg, vm, vm_part, sums, counter);

  dim3 ggrid(MT, MT, NB);
  hinge_gemm<<<ggrid, 256, 0, stream>>>(Ap, Bp, wg, vm, vm_part,
                                        sums, counter, out);
}

// Round 4
// 190.283 us; speedup vs baseline: 1.0287x; 1.0287x over previous
//
#include <hip/hip_runtime.h>
#include <stdint.h>

// Problem constants (from reference)
#define NB   4      // batch
#define CC   256    // channels (K)
#define WR   60     // cells per row/col
#define MM   3600   // HR*WR (M and N of the GEMM)
#define HH   480
#define WW   480
#define GS   8
#define MT   29     // ceil(3600/128) tiles per side
#define NBLK (MT * MT * NB)      // gemm grid size = 3364
#define PREPB 57                 // ceil(NB*MM / 256) blocks carrying prep work

typedef __bf16 bf16x8 __attribute__((ext_vector_type(8)));
typedef float  f32x4  __attribute__((ext_vector_type(4)));

// round-to-nearest-even fp32 -> bf16 (data has no NaN/inf)
__device__ __forceinline__ unsigned short f2bf(float x) {
  union { float f; unsigned u; } v; v.f = x;
  unsigned r = v.u + 0x7fffu + ((v.u >> 16) & 1u);
  return (unsigned short)(r >> 16);
}

// async global->LDS, 16B per lane; LDS dest is wave-uniform base + lane*16
__device__ __forceinline__ void gload_lds16(const void* g, void* l) {
  __builtin_amdgcn_global_load_lds(
      (const __attribute__((address_space(1))) void*)g,
      (__attribute__((address_space(3))) void*)l, 16, 0, 0);
}

// ---------------------------------------------------------------------------
// Kernel 1: pack desc[b][c][m] (f32) into MFMA-fragment-ordered bf16 tiles:
//   packed[b][mtile][kt][ ((h*4 + t)*64 + lane)*8 + e ]
// (m = mtile*128 + h*64 + t*16 + (lane&15), k = kt*32 + (lane>>4)*8 + e).
// Tail rows (m >= 3600) zero-filled -> GEMM needs no m-guard.
// FUSED: blocks 0..56 also do the per-cell prep (homography warp, vis-mask
// 8x8 product, per-block vm partial sums); block 0 zeroes loss+counter.
// ---------------------------------------------------------------------------
__global__ __launch_bounds__(256) void pack_prep(
    const float* __restrict__ d1, const float* __restrict__ d2,
    const float* __restrict__ homo, const float* __restrict__ vis,
    unsigned short* __restrict__ p1, unsigned short* __restrict__ p2,
    float2* __restrict__ wg, float* __restrict__ vmarr,
    float* __restrict__ vm_part, float* __restrict__ loss_sum,
    unsigned* __restrict__ counter) {
  __shared__ float tile[32][132];   // [k_local][m_local]; rows 528B (16B-aligned)
  int kt = blockIdx.x, mtile = blockIdx.y, z = blockIdx.z;
  int bid = kt + 8 * (mtile + MT * z);
  int b = z & 3;
  const float* src = ((z >> 2) ? d2 : d1) + (size_t)b * CC * MM + (size_t)(kt * 32) * MM;
  unsigned short* dst = ((z >> 2) ? p2 : p1) + ((size_t)(b * MT + mtile) * 8 + kt) * 4096;
  int tid = threadIdx.x;

  if (bid == 0 && tid == 0) { loss_sum[0] = 0.f; *counter = 0u; }

  // coalesced read: 32 k-rows x 128 m (float4 along m)
#pragma unroll
  for (int pass = 0; pass < 4; ++pass) {
    int cid = pass * 256 + tid;          // [0,1024)
    int c = cid >> 5, m4 = (cid & 31) * 4;
    int gm = mtile * 128 + m4;
    float4 v;
    if (gm + 3 < MM) {
      v = *(const float4*)(src + (size_t)c * MM + gm);
    } else {
      v.x = (gm     < MM) ? src[(size_t)c * MM + gm]     : 0.f;
      v.y = (gm + 1 < MM) ? src[(size_t)c * MM + gm + 1] : 0.f;
      v.z = (gm + 2 < MM) ? src[(size_t)c * MM + gm + 2] : 0.f;
      v.w = (gm + 3 < MM) ? src[(size_t)c * MM + gm + 3] : 0.f;
    }
    *(float4*)&tile[c][m4] = v;
  }
  __syncthreads();

  // fragment-order write: 512 slots of 16B; slot s = ((h*4+t)*64 + lane)
#pragma unroll
  for (int pass = 0; pass < 2; ++pass) {
    int s = pass * 256 + tid;            // [0,512)
    int lane = s & 63, tt = (s >> 6) & 3, h = s >> 8;
    int m_local = h * 64 + tt * 16 + (lane & 15);
    int k_local = (lane >> 4) * 8;
    unsigned short o[8];
    if (mtile * 128 + m_local < MM) {
#pragma unroll
      for (int e = 0; e < 8; ++e) o[e] = f2bf(tile[k_local + e][m_local]);
    } else {
#pragma unroll
      for (int e = 0; e < 8; ++e) o[e] = 0;
    }
    ((uint4*)dst)[s] = *(const uint4*)o;
  }

  // ---- fused prep (blocks 0..56 only; block-uniform branch) ----
  if (bid < PREPB) {
    int idx = bid * 256 + tid;
    float p = 0.f;
    if (idx < NB * MM) {
      int bb = idx / MM, cell = idx - bb * MM;
      int h1 = cell / WR, w1 = cell - h1 * WR;
      float gx = (float)(w1 * GS + GS / 2);
      float gy = (float)(h1 * GS + GS / 2);
      const float* Hm = homo + bb * 9;
      float X = Hm[0] * gx + Hm[1] * gy + Hm[2];
      float Y = Hm[3] * gx + Hm[4] * gy + Hm[5];
      float Z = Hm[6] * gx + Hm[7] * gy + Hm[8];
      wg[idx] = make_float2(X / Z, Y / Z);
      const float* v = vis + (size_t)bb * HH * WW + (size_t)(h1 * GS) * WW + w1 * GS;
      float prod = 1.f;
#pragma unroll
      for (int rr = 0; rr < GS; ++rr) {
        const float4* rp = (const float4*)(v + (size_t)rr * WW);
        float4 a = rp[0], c = rp[1];
        prod *= a.x * a.y * a.z * a.w;
        prod *= c.x * c.y * c.z * c.w;
      }
      vmarr[idx] = prod;
      p = prod;
    }
#pragma unroll
    for (int off = 32; off; off >>= 1) p += __shfl_down(p, off, 64);
    __syncthreads();                      // tile LDS reuse safety
    if ((tid & 63) == 0) ((float*)tile)[tid >> 6] = p;
    __syncthreads();
    if (tid == 0)
      vm_part[bid] = ((float*)tile)[0] + ((float*)tile)[1] +
                     ((float*)tile)[2] + ((float*)tile)[3];
  }
}

// ---------------------------------------------------------------------------
// Kernel 2: fused bf16 MFMA GEMM + hinge loss + global reduce + finalize.
// Round-2 structure (128x128 tile, frag-packed conflict-free LDS) plus
// DOUBLE-BUFFERED A and B kt-tiles: prefetch(kt+1) issued before compute(kt),
// so the barrier's vmcnt(0) drain lands after the MFMA phase. LDS = 32 KB
// exactly -> 4 blocks/CU (launch_bounds(256,4)); cross-block overlap fills
// the residual load-latency stalls. Last block finalizes the output.
// ---------------------------------------------------------------------------
__global__ __launch_bounds__(256, 4) void hinge_gemm(
    const unsigned short* __restrict__ Ap, const unsigned short* __restrict__ Bp,
    const float2* __restrict__ wg, const float* __restrict__ vmarr,
    const float* __restrict__ vm_part, float* __restrict__ loss_sum,
    unsigned* __restrict__ counter, float* __restrict__ out) {
  __shared__ unsigned short As[8192];   // 2 x 8 KB A dbuf
  __shared__ unsigned short Bs[8192];   // 2 x 8 KB B dbuf

  int b = blockIdx.z, mtile = blockIdx.y, ntile = blockIdx.x;
  int tid = threadIdx.x, lane = tid & 63, w = tid >> 6;
  int quad = lane >> 4, r = lane & 15;
  int wave_m = w >> 1, wave_n = w & 1;

  const char* Ag = (const char*)(Ap + ((size_t)(b * MT + mtile) * 8) * 4096);
  const char* Bg = (const char*)(Bp + ((size_t)(b * MT + ntile) * 8) * 4096);
  char* AsB = (char*)As;
  char* BsB = (char*)Bs;

  // stage kt=0 into buffer 0
  gload_lds16(Ag + tid * 16,        AsB + w * 1024);
  gload_lds16(Ag + 4096 + tid * 16, AsB + 4096 + w * 1024);
  gload_lds16(Bg + tid * 16,        BsB + w * 1024);
  gload_lds16(Bg + 4096 + tid * 16, BsB + 4096 + w * 1024);

  f32x4 acc[4][4];
#pragma unroll
  for (int i = 0; i < 4; ++i)
#pragma unroll
    for (int j = 0; j < 4; ++j)
#pragma unroll
      for (int k = 0; k < 4; ++k) acc[i][j][k] = 0.f;

  __syncthreads();

#pragma unroll
  for (int kt = 0; kt < 8; ++kt) {
    if (kt < 7) {   // prefetch kt+1 into the other buffer BEFORE compute
      const char* ga = Ag + (kt + 1) * 8192;
      const char* gb = Bg + (kt + 1) * 8192;
      char* an = AsB + ((kt + 1) & 1) * 8192;
      char* bn = BsB + ((kt + 1) & 1) * 8192;
      gload_lds16(ga + tid * 16,        an + w * 1024);
      gload_lds16(ga + 4096 + tid * 16, an + 4096 + w * 1024);
      gload_lds16(gb + tid * 16,        bn + w * 1024);
      gload_lds16(gb + 4096 + tid * 16, bn + 4096 + w * 1024);
    }
    const char* pa = AsB + (kt & 1) * 8192 + wave_m * 4096 + lane * 16;
    const char* pb = BsB + (kt & 1) * 8192 + wave_n * 4096 + lane * 16;
    bf16x8 af[4], bfr[4];
#pragma unroll
    for (int t = 0; t < 4; ++t) {
      af[t]  = *(const bf16x8*)(pa + t * 1024);
      bfr[t] = *(const bf16x8*)(pb + t * 1024);
    }
#pragma unroll
    for (int mt = 0; mt < 4; ++mt)
#pragma unroll
      for (int nt = 0; nt < 4; ++nt)
        acc[mt][nt] = __builtin_amdgcn_mfma_f32_16x16x32_bf16(
            af[mt], bfr[nt], acc[mt][nt], 0, 0, 0);
    __syncthreads();   // read-done for buf kt&1 + drain of prefetch kt+1
  }

  // Epilogue. C/D layout: col(n) = lane&15, row(m) = quad*4 + reg.
  // Tail m-rows are zero-padded in Ap -> dot=0 -> hinge=0; no m-guard needed.
  float gxv[16], gyv[16];
#pragma unroll
  for (int mt = 0; mt < 4; ++mt)
#pragma unroll
    for (int reg = 0; reg < 4; ++reg) {
      int gm = mtile * 128 + wave_m * 64 + mt * 16 + quad * 4 + reg;
      float gmf = (float)gm;
      float h1 = floorf(fmaf(gmf, (1.0f / 60.0f), (1.0f / 120.0f)));
      float w1 = fmaf(h1, -60.f, gmf);
      gxv[mt * 4 + reg] = fmaf(w1, 8.f, 4.f);
      gyv[mt * 4 + reg] = fmaf(h1, 8.f, 4.f);
    }

  float sum = 0.f;
  const float2* wgb = wg + (size_t)b * MM;
  const float*  vmb = vmarr + (size_t)b * MM;
#pragma unroll
  for (int nt = 0; nt < 4; ++nt) {
    int gn = ntile * 128 + wave_n * 64 + nt * 16 + r;
    bool nok = gn < MM;
    float2 wgv = nok ? wgb[gn] : make_float2(1e9f, 1e9f);
    float  vmv = nok ? vmb[gn] : 0.f;
#pragma unroll
    for (int mt = 0; mt < 4; ++mt)
#pragma unroll
      for (int reg = 0; reg < 4; ++reg) {
        float dot = acc[mt][nt][reg];
        float dx = gxv[mt * 4 + reg] - wgv.x;
        float dy = gyv[mt * 4 + reg] - wgv.y;
        float d2 = fmaf(dx, dx, dy * dy);
        float a = (d2 <= 56.25f) ? (1.0f - dot) : (dot - 0.2f);
        sum = fmaf(vmv, fmaxf(a, 0.f), sum);
      }
  }
#pragma unroll
  for (int off = 32; off; off >>= 1) sum += __shfl_down(sum, off, 64);
  if (lane == 0) ((float*)As)[w] = sum;   // reuse As (all LDS reads done)
  __syncthreads();
  if (tid == 0) {
    float bs = ((float*)As)[0] + ((float*)As)[1] +
               ((float*)As)[2] + ((float*)As)[3];
    atomicAdd(loss_sum, bs);
    __threadfence();
    unsigned old = atomicAdd(counter, 1u);
    if (old == (unsigned)NBLK - 1u) {     // last block: finalize
      float vs = 0.f;
      for (int i = 0; i < PREPB; ++i) vs += vm_part[i];
      float lt = atomicAdd(loss_sum, 0.f);  // atomic read: all adds visible
      out[0] = lt / ((float)MM * vs);
    }
  }
}

extern "C" void kernel_launch(void* const* d_in, const int* in_sizes, int n_in,
                              void* d_out, int out_size, void* d_ws, size_t ws_size,
                              hipStream_t stream) {
  const float* desc1 = (const float*)d_in[0];
  const float* desc2 = (const float*)d_in[1];
  const float* homo  = (const float*)d_in[2];
  const float* vis   = (const float*)d_in[3];
  float* out = (float*)d_out;

  char* ws = (char*)d_ws;
  // packed size per desc: 4 * 29 * 8 * 4096 elems * 2B = 7,602,176 B
  unsigned short* Ap = (unsigned short*)ws;
  unsigned short* Bp = (unsigned short*)(ws + 7602176);
  float2*   wg      = (float2*)(ws + 15204352);          // 115,200 B
  float*    vm      = (float*) (ws + 15319552);          //  57,600 B
  float*    vm_part = (float*) (ws + 15377152);          // 57 * 4 B
  float*    sums    = (float*) (ws + 15377408);          // loss accumulator
  unsigned* counter = (unsigned*)(ws + 15377412);

  dim3 pgrid(8, MT, 2 * NB);   // kt x mtile x (desc,b); fused prep + zero-init
  pack_prep<<<pgrid, 256, 0, stream>>>(desc1, desc2, homo, vis, Ap, Bp,
                                       wg, vm, vm_part, sums, counter);

  dim3 ggrid(MT, MT, NB);
  hinge_gemm<<<ggrid, 256, 0, stream>>>(Ap, Bp, wg, vm, vm_part,
                                        sums, counter, out);
}

// Round 5
// 178.388 us; speedup vs baseline: 1.0973x; 1.0667x over previous
//
#include <hip/hip_runtime.h>
#include <stdint.h>

// Problem constants (from reference)
#define NB   4      // batch
#define CC   256    // channels (K)
#define WR   60     // cells per row/col
#define MM   3600   // HR*WR (M and N of the GEMM)
#define HH   480
#define WW   480
#define GS   8
#define MT   29     // ceil(3600/128) tiles per side
#define NBLK (MT * MT * NB)      // gemm grid size = 3364
#define PREPB 57                 // ceil(NB*MM / 256) blocks carrying prep work

typedef float f32x4 __attribute__((ext_vector_type(4)));

// async global->LDS, 16B per lane; LDS dest is wave-uniform base + lane*16
__device__ __forceinline__ void gload_lds16(const void* g, void* l) {
  __builtin_amdgcn_global_load_lds(
      (const __attribute__((address_space(1))) void*)g,
      (__attribute__((address_space(3))) void*)l, 16, 0, 0);
}

// ---------------------------------------------------------------------------
// Kernel 1: pack desc[b][c][m] (f32) into MFMA-fragment-ordered fp8-e4m3:
//   packed[b][mtile][kt][ slot = (h*4 + t)*64 + lane ][8 fp8]
// where m = mtile*128 + h*64 + t*16 + (lane&15), k = kt*32 + (lane>>4)*8 + e.
// Same verified lane mapping as the bf16 16x16x32 MFMA (m=lane&15,
// k=quad*8+j); tile is now 4096 B. Tail rows zero-filled (fp8 0 == 0x00).
// FUSED: blocks 0..56 also do per-cell prep; block 0 zeroes loss+counter.
// ---------------------------------------------------------------------------
__global__ __launch_bounds__(256) void pack_prep(
    const float* __restrict__ d1, const float* __restrict__ d2,
    const float* __restrict__ homo, const float* __restrict__ vis,
    unsigned char* __restrict__ p1, unsigned char* __restrict__ p2,
    float2* __restrict__ wg, float* __restrict__ vmarr,
    float* __restrict__ vm_part, float* __restrict__ loss_sum,
    unsigned* __restrict__ counter) {
  __shared__ float tile[32][132];   // [k_local][m_local]; rows 528B (16B-aligned)
  int kt = blockIdx.x, mtile = blockIdx.y, z = blockIdx.z;
  int bid = kt + 8 * (mtile + MT * z);
  int b = z & 3;
  const float* src = ((z >> 2) ? d2 : d1) + (size_t)b * CC * MM + (size_t)(kt * 32) * MM;
  unsigned char* dst = ((z >> 2) ? p2 : p1) + ((size_t)(b * MT + mtile) * 8 + kt) * 4096;
  int tid = threadIdx.x;

  if (bid == 0 && tid == 0) { loss_sum[0] = 0.f; *counter = 0u; }

  // coalesced read: 32 k-rows x 128 m (float4 along m)
#pragma unroll
  for (int pass = 0; pass < 4; ++pass) {
    int cid = pass * 256 + tid;          // [0,1024)
    int c = cid >> 5, m4 = (cid & 31) * 4;
    int gm = mtile * 128 + m4;
    float4 v;
    if (gm + 3 < MM) {
      v = *(const float4*)(src + (size_t)c * MM + gm);
    } else {
      v.x = (gm     < MM) ? src[(size_t)c * MM + gm]     : 0.f;
      v.y = (gm + 1 < MM) ? src[(size_t)c * MM + gm + 1] : 0.f;
      v.z = (gm + 2 < MM) ? src[(size_t)c * MM + gm + 2] : 0.f;
      v.w = (gm + 3 < MM) ? src[(size_t)c * MM + gm + 3] : 0.f;
    }
    *(float4*)&tile[c][m4] = v;
  }
  __syncthreads();

  // fragment-order write: 512 slots of 8B; slot s = ((h*4+t)*64 + lane)
#pragma unroll
  for (int pass = 0; pass < 2; ++pass) {
    int s = pass * 256 + tid;            // [0,512)
    int lane = s & 63, tt = (s >> 6) & 3, h = s >> 8;
    int m_local = h * 64 + tt * 16 + (lane & 15);
    int k_local = (lane >> 4) * 8;
    int w01 = 0, w23 = 0;
    if (mtile * 128 + m_local < MM) {
      float f0 = tile[k_local + 0][m_local], f1 = tile[k_local + 1][m_local];
      float f2 = tile[k_local + 2][m_local], f3 = tile[k_local + 3][m_local];
      float f4 = tile[k_local + 4][m_local], f5 = tile[k_local + 5][m_local];
      float f6 = tile[k_local + 6][m_local], f7 = tile[k_local + 7][m_local];
      w01 = __builtin_amdgcn_cvt_pk_fp8_f32(f0, f1, 0, false);
      w01 = __builtin_amdgcn_cvt_pk_fp8_f32(f2, f3, w01, true);
      w23 = __builtin_amdgcn_cvt_pk_fp8_f32(f4, f5, 0, false);
      w23 = __builtin_amdgcn_cvt_pk_fp8_f32(f6, f7, w23, true);
    }
    ((int2*)dst)[s] = make_int2(w01, w23);
  }

  // ---- fused prep (blocks 0..56 only; block-uniform branch) ----
  if (bid < PREPB) {
    int idx = bid * 256 + tid;
    float p = 0.f;
    if (idx < NB * MM) {
      int bb = idx / MM, cell = idx - bb * MM;
      int h1 = cell / WR, w1 = cell - h1 * WR;
      float gx = (float)(w1 * GS + GS / 2);
      float gy = (float)(h1 * GS + GS / 2);
      const float* Hm = homo + bb * 9;
      float X = Hm[0] * gx + Hm[1] * gy + Hm[2];
      float Y = Hm[3] * gx + Hm[4] * gy + Hm[5];
      float Z = Hm[6] * gx + Hm[7] * gy + Hm[8];
      wg[idx] = make_float2(X / Z, Y / Z);
      const float* v = vis + (size_t)bb * HH * WW + (size_t)(h1 * GS) * WW + w1 * GS;
      float prod = 1.f;
#pragma unroll
      for (int rr = 0; rr < GS; ++rr) {
        const float4* rp = (const float4*)(v + (size_t)rr * WW);
        float4 a = rp[0], c = rp[1];
        prod *= a.x * a.y * a.z * a.w;
        prod *= c.x * c.y * c.z * c.w;
      }
      vmarr[idx] = prod;
      p = prod;
    }
#pragma unroll
    for (int off = 32; off; off >>= 1) p += __shfl_down(p, off, 64);
    __syncthreads();                      // tile LDS reuse safety
    if ((tid & 63) == 0) ((float*)tile)[tid >> 6] = p;
    __syncthreads();
    if (tid == 0)
      vm_part[bid] = ((float*)tile)[0] + ((float*)tile)[1] +
                     ((float*)tile)[2] + ((float*)tile)[3];
  }
}

// ---------------------------------------------------------------------------
// Kernel 2: fused fp8 MFMA GEMM + hinge loss + global reduce + finalize.
// EXACT round-2 K-loop shape (single-buffered, loads; sync; compute; sync —
// the known-good 66 µs structure; both pipelining attempts regressed 2x),
// with fp8-e4m3 tiles: 4 KB/tile, 2 global_load_lds per iter (half the DMA
// volume of bf16). mfma_f32_16x16x32_fp8_fp8, same C/D layout as bf16.
// Fragment ds_read_b64 is lane-linear x8B -> 2-way bank alias (free, m136).
// ---------------------------------------------------------------------------
__global__ __launch_bounds__(256, 4) void hinge_gemm(
    const unsigned char* __restrict__ Ap, const unsigned char* __restrict__ Bp,
    const float2* __restrict__ wg, const float* __restrict__ vmarr,
    const float* __restrict__ vm_part, float* __restrict__ loss_sum,
    unsigned* __restrict__ counter, float* __restrict__ out) {
  __shared__ unsigned char As[4096];   // one kt-tile, 4 KB
  __shared__ unsigned char Bs[4096];
  __shared__ float partial[4];

  int b = blockIdx.z, mtile = blockIdx.y, ntile = blockIdx.x;
  int tid = threadIdx.x, lane = tid & 63, w = tid >> 6;
  int quad = lane >> 4, r = lane & 15;
  int wave_m = w >> 1, wave_n = w & 1;

  const char* Ag = (const char*)(Ap + ((size_t)(b * MT + mtile) * 8) * 4096);
  const char* Bg = (const char*)(Bp + ((size_t)(b * MT + ntile) * 8) * 4096);
  char* AsB = (char*)As;
  char* BsB = (char*)Bs;

  f32x4 acc[4][4];
#pragma unroll
  for (int i = 0; i < 4; ++i)
#pragma unroll
    for (int j = 0; j < 4; ++j)
#pragma unroll
      for (int k = 0; k < 4; ++k) acc[i][j][k] = 0.f;

  // fragment base: per t-tile 64 lanes x 8B = 512B; per wave-half 2KB
  const char* pa = AsB + wave_m * 2048 + lane * 8;
  const char* pb = BsB + wave_n * 2048 + lane * 8;

  for (int kt = 0; kt < 8; ++kt) {
    gload_lds16(Ag + kt * 4096 + tid * 16, AsB + w * 1024);
    gload_lds16(Bg + kt * 4096 + tid * 16, BsB + w * 1024);
    __syncthreads();

    long af[4], bfr[4];
#pragma unroll
    for (int t = 0; t < 4; ++t) {
      af[t]  = *(const long*)(pa + t * 512);
      bfr[t] = *(const long*)(pb + t * 512);
    }
#pragma unroll
    for (int mt = 0; mt < 4; ++mt)
#pragma unroll
      for (int nt = 0; nt < 4; ++nt)
        acc[mt][nt] = __builtin_amdgcn_mfma_f32_16x16x32_fp8_fp8(
            af[mt], bfr[nt], acc[mt][nt], 0, 0, 0);
    __syncthreads();
  }

  // Epilogue. C/D layout: col(n) = lane&15, row(m) = quad*4 + reg.
  // Tail m-rows are zero-padded in Ap -> dot=0 -> hinge=0; no m-guard needed.
  float gxv[16], gyv[16];
#pragma unroll
  for (int mt = 0; mt < 4; ++mt)
#pragma unroll
    for (int reg = 0; reg < 4; ++reg) {
      int gm = mtile * 128 + wave_m * 64 + mt * 16 + quad * 4 + reg;
      float gmf = (float)gm;
      float h1 = floorf(fmaf(gmf, (1.0f / 60.0f), (1.0f / 120.0f)));
      float w1 = fmaf(h1, -60.f, gmf);
      gxv[mt * 4 + reg] = fmaf(w1, 8.f, 4.f);
      gyv[mt * 4 + reg] = fmaf(h1, 8.f, 4.f);
    }

  float sum = 0.f;
  const float2* wgb = wg + (size_t)b * MM;
  const float*  vmb = vmarr + (size_t)b * MM;
#pragma unroll
  for (int nt = 0; nt < 4; ++nt) {
    int gn = ntile * 128 + wave_n * 64 + nt * 16 + r;
    bool nok = gn < MM;
    float2 wgv = nok ? wgb[gn] : make_float2(1e9f, 1e9f);
    float  vmv = nok ? vmb[gn] : 0.f;
#pragma unroll
    for (int mt = 0; mt < 4; ++mt)
#pragma unroll
      for (int reg = 0; reg < 4; ++reg) {
        float dot = acc[mt][nt][reg];
        float dx = gxv[mt * 4 + reg] - wgv.x;
        float dy = gyv[mt * 4 + reg] - wgv.y;
        float d2 = fmaf(dx, dx, dy * dy);
        float a = (d2 <= 56.25f) ? (1.0f - dot) : (dot - 0.2f);
        sum = fmaf(vmv, fmaxf(a, 0.f), sum);
      }
  }
#pragma unroll
  for (int off = 32; off; off >>= 1) sum += __shfl_down(sum, off, 64);
  if (lane == 0) partial[w] = sum;
  __syncthreads();
  if (tid == 0) {
    float bs = partial[0] + partial[1] + partial[2] + partial[3];
    atomicAdd(loss_sum, bs);
    __threadfence();
    unsigned old = atomicAdd(counter, 1u);
    if (old == (unsigned)NBLK - 1u) {     // last block: finalize
      float vs = 0.f;
      for (int i = 0; i < PREPB; ++i) vs += vm_part[i];
      float lt = atomicAdd(loss_sum, 0.f);  // atomic read: all adds visible
      out[0] = lt / ((float)MM * vs);
    }
  }
}

extern "C" void kernel_launch(void* const* d_in, const int* in_sizes, int n_in,
                              void* d_out, int out_size, void* d_ws, size_t ws_size,
                              hipStream_t stream) {
  const float* desc1 = (const float*)d_in[0];
  const float* desc2 = (const float*)d_in[1];
  const float* homo  = (const float*)d_in[2];
  const float* vis   = (const float*)d_in[3];
  float* out = (float*)d_out;

  char* ws = (char*)d_ws;
  // packed size per desc: 4 * 29 * 8 * 4096 B = 3,801,088 B
  unsigned char* Ap = (unsigned char*)ws;
  unsigned char* Bp = (unsigned char*)(ws + 3801088);
  float2*   wg      = (float2*)(ws + 7602176);           // 115,200 B
  float*    vm      = (float*) (ws + 7717376);           //  57,600 B
  float*    vm_part = (float*) (ws + 7774976);           // 57 * 4 B
  float*    sums    = (float*) (ws + 7775232);           // loss accumulator
  unsigned* counter = (unsigned*)(ws + 7775236);

  dim3 pgrid(8, MT, 2 * NB);   // kt x mtile x (desc,b); fused prep + zero-init
  pack_prep<<<pgrid, 256, 0, stream>>>(desc1, desc2, homo, vis, Ap, Bp,
                                       wg, vm, vm_part, sums, counter);

  dim3 ggrid(MT, MT, NB);
  hinge_gemm<<<ggrid, 256, 0, stream>>>(Ap, Bp, wg, vm, vm_part,
                                        sums, counter, out);
}